// Round 6
// baseline (1706.336 us; speedup 1.0000x reference)
//
#include <hip/hip_runtime.h>

#define H 128

// ---------------------------------------------------------------------------
// R5: coarse bucket sort (256 nodes/bucket, 196 buckets) via block-synchronous
// multisplit (LDS rank + batch reservation -> run-contiguous writes), then
// per-bucket LDS-resident aggregation (256x128 f32 = 128 KB, ds_add_f32).
// No per-node CSR, no global atomics on feature rows, no linked lists (R4 bad).
// mlp2/mlp3 unchanged from R3. Layer-1 scalar agg fused into bin_scatter.
//
// Workspace (4-byte words):
//   consts[1024] | sp[E] (u64: hi = src | dstlow<<16, lo = ea bits)
//   | bufA[N*H] (t2, later t3) | h2b[N*H bf16] | s1[N] | p[N] | q[N]
//   | bhist[256] | rowb[257] | cursor[256]
// Requires N <= 65536 (src packed in 16 bits). N = 50000.
// ---------------------------------------------------------------------------

typedef unsigned long long ull;

__device__ __forceinline__ float4 f4fma(float s, float4 w, float4 a) {
  a.x = fmaf(s, w.x, a.x); a.y = fmaf(s, w.y, a.y);
  a.z = fmaf(s, w.z, a.z); a.w = fmaf(s, w.w, a.w);
  return a;
}

__device__ __forceinline__ float bf2f(unsigned short v) {
  return __uint_as_float(((unsigned)v) << 16);
}

__device__ __forceinline__ unsigned bf16pair(float a, float b) {
  unsigned ua = __float_as_uint(a), ub = __float_as_uint(b);
  ua = (ua + 0x7FFFu + ((ua >> 16) & 1u)) >> 16;   // RNE
  ub = (ub + 0x7FFFu + ((ub >> 16) & 1u)) >> 16;
  return (ua & 0xFFFFu) | (ub << 16);
}

// blocks 0..NB-1: s1 = x (block 0 also zeroes bhist); last block: consts
__global__ void init_kernel(
    const float* __restrict__ x, float* __restrict__ s1,
    int* __restrict__ bhist, int N,
    const float* __restrict__ em_w, const float* __restrict__ em_b,
    const float* __restrict__ l1_w, const float* __restrict__ l1_b,
    const float* __restrict__ l2_w, const float* __restrict__ l2_b,
    const float* __restrict__ n1_b,
    const float* __restrict__ l3_w, const float* __restrict__ l3_b,
    float* __restrict__ consts) {
  if (blockIdx.x == gridDim.x - 1) {
    const int k = threadIdx.x;
    __shared__ float sa[H], sc[H];
    if (k < H) {
      float u2 = 0.f, c2 = 0.f, u3 = 0.f, c3 = 0.f;
      for (int j = 0; j < H; ++j) {
        const float ew = em_w[j], eb = em_b[j];
        u2 = fmaf(ew, l2_w[j * H + k], u2);
        c2 = fmaf(eb, l2_w[j * H + k], c2);
        u3 = fmaf(ew, l3_w[j * H + k], u3);
        c3 = fmaf(eb, l3_w[j * H + k], c3);
      }
      consts[2 + k]         = u2;
      consts[2 + H + k]     = c2 + l2_b[k] + n1_b[k];
      consts[2 + 2 * H + k] = u3;
      consts[2 + 3 * H + k] = c3 + l3_b[k];
      sa[k] = em_w[k] * l1_w[k];
      sc[k] = em_b[k] * l1_w[k];
    }
    __syncthreads();
    for (int s = 64; s > 0; s >>= 1) {
      if (k < s) { sa[k] += sa[k + s]; sc[k] += sc[k + s]; }
      __syncthreads();
    }
    if (k == 0) { consts[0] = sa[0]; consts[1] = sc[0] + l1_b[0]; }
  } else {
    const int n = blockIdx.x * blockDim.x + threadIdx.x;
    if (n < N) s1[n] = x[n];
    if (blockIdx.x == 0) bhist[threadIdx.x] = 0;
  }
}

// per-block LDS histogram of dst>>8, merged to global
__global__ __launch_bounds__(256) void bucket_hist(
    const int* __restrict__ dst, int* __restrict__ bhist, int E) {
  __shared__ int lh[256];
  const int tid = threadIdx.x;
  lh[tid] = 0;
  __syncthreads();
  const int stride = gridDim.x * blockDim.x;
  for (int e = blockIdx.x * blockDim.x + tid; e < E; e += stride)
    atomicAdd(&lh[dst[e] >> 8], 1);
  __syncthreads();
  if (lh[tid]) atomicAdd(&bhist[tid], lh[tid]);
}

// single block, 256-wide Hillis-Steele scan of <=256 bucket counts
__global__ __launch_bounds__(256) void bucket_scan(
    const int* __restrict__ bhist, int* __restrict__ rowb,
    int* __restrict__ cursor, int NBUCK) {
  __shared__ int sd[256];
  const int tid = threadIdx.x;
  const int v = (tid < NBUCK) ? bhist[tid] : 0;
  sd[tid] = v;
  __syncthreads();
  for (int off = 1; off < 256; off <<= 1) {
    const int t = (tid >= off) ? sd[tid - off] : 0;
    __syncthreads();
    sd[tid] += t;
    __syncthreads();
  }
  if (tid < NBUCK) { rowb[tid] = sd[tid] - v; cursor[tid] = sd[tid] - v; }
  if (tid == 255) rowb[NBUCK] = sd[255];
}

// block-synchronous multisplit: batch of 4096 edges per block.
// LDS rank within batch + one global reservation per (bucket,batch) ->
// bucket runs written contiguously (~170 B avg). Fused layer-1 scalar agg.
__global__ __launch_bounds__(1024) void bin_scatter(
    const int* __restrict__ src, const int* __restrict__ dst,
    const float* __restrict__ ea, const float* __restrict__ x,
    const float* __restrict__ consts, int* __restrict__ cursor,
    ull* __restrict__ sp, float* __restrict__ s1, int E, int NBUCK) {
  __shared__ int lhist[256];
  __shared__ int lbase[256];
  const int tid = threadIdx.x;
  const int base = blockIdx.x * 4096 + tid * 4;
  if (tid < 256) lhist[tid] = 0;
  __syncthreads();
  int s_[4], d_[4], b_[4], r_[4];
  float a_[4];
#pragma unroll
  for (int j = 0; j < 4; ++j) {
    const int e = base + j;
    if (e < E) {
      s_[j] = src[e]; d_[j] = dst[e]; a_[j] = ea[e];
      b_[j] = d_[j] >> 8;
      r_[j] = atomicAdd(&lhist[b_[j]], 1);
    } else {
      b_[j] = -1;
    }
  }
  __syncthreads();
  if (tid < NBUCK && lhist[tid] > 0)
    lbase[tid] = atomicAdd(&cursor[tid], lhist[tid]);
  __syncthreads();
  const float a1 = consts[0], c1 = consts[1];
#pragma unroll
  for (int j = 0; j < 4; ++j) {
    if (b_[j] >= 0) {
      const int pos = lbase[b_[j]] + r_[j];
      sp[pos] = ((ull)(unsigned)(s_[j] | ((d_[j] & 255) << 16)) << 32) |
                (ull)(unsigned)__float_as_uint(a_[j]);
      const float m = fmaxf(x[s_[j]] + fmaf(a1, a_[j], c1), 0.f);
      unsafeAtomicAdd(&s1[d_[j]], m);
    }
  }
}

// per-bucket LDS aggregation, layer 2:
// agg[dl][k] += relu(s1[src]*n1w[k] + ea*u2[k] + c2[k]); then
// t2[n,k] = s1[n]*n1w[k] + n1b[k] + agg
__global__ __launch_bounds__(1024) void agg2_kernel(
    const int* __restrict__ rowb, const ull* __restrict__ sp,
    const float* __restrict__ s1, const float* __restrict__ n1w,
    const float* __restrict__ n1b, const float* __restrict__ consts,
    float* __restrict__ t2, int N) {
  __shared__ float agg[256 * H];  // 128 KB
  const int tid = threadIdx.x;
  const float4 z = make_float4(0.f, 0.f, 0.f, 0.f);
#pragma unroll
  for (int i = 0; i < 8; ++i) ((float4*)agg)[tid + i * 1024] = z;
  __syncthreads();
  const int lane = tid & 63, wid = tid >> 6;
  const float w0 = n1w[lane],            w1 = n1w[lane + 64];
  const float u0 = consts[2 + lane],     u1 = consts[2 + lane + 64];
  const float c0 = consts[2 + H + lane], c1 = consts[2 + H + lane + 64];
  const int rs = rowb[blockIdx.x], re = rowb[blockIdx.x + 1];
  for (int base0 = rs + wid * 64; base0 < re; base0 += 1024) {
    const int i = base0 + lane;
    float sv = 0.f, av = 0.f;
    int dl = 0;
    if (i < re) {
      const ull pay = sp[i];
      const unsigned hi = (unsigned)(pay >> 32);
      av = __uint_as_float((unsigned)pay);
      sv = s1[hi & 0xFFFFu];
      dl = (int)((hi >> 16) & 255u);
    }
    const int cnt = min(64, re - base0);
    for (int j = 0; j < cnt; ++j) {
      const float s = __shfl(sv, j, 64);
      const float a = __shfl(av, j, 64);
      const int d = __shfl(dl, j, 64);
      atomicAdd(&agg[d * H + lane],      fmaxf(fmaf(s, w0, fmaf(a, u0, c0)), 0.f));
      atomicAdd(&agg[d * H + lane + 64], fmaxf(fmaf(s, w1, fmaf(a, u1, c1)), 0.f));
    }
  }
  __syncthreads();
  for (int idx = tid; idx < 256 * H; idx += 1024) {
    const int nn = idx >> 7, k = idx & (H - 1);
    const int n = (blockIdx.x << 8) + nn;
    if (n < N) t2[(size_t)n * H + k] = fmaf(s1[n], n1w[k], n1b[k]) + agg[idx];
  }
}

// per-bucket LDS aggregation, layer 3 (bf16 h2 gathers):
// agg[dl][k] += relu(h2[src,k] + ea*u3[k] + c3[k]); t3 = h2[n] + agg
__global__ __launch_bounds__(1024) void agg3_kernel(
    const int* __restrict__ rowb, const ull* __restrict__ sp,
    const unsigned short* __restrict__ h2b, const float* __restrict__ consts,
    float* __restrict__ t3, int N) {
  __shared__ float agg[256 * H];  // 128 KB
  const int tid = threadIdx.x;
  const float4 z = make_float4(0.f, 0.f, 0.f, 0.f);
#pragma unroll
  for (int i = 0; i < 8; ++i) ((float4*)agg)[tid + i * 1024] = z;
  __syncthreads();
  const int lane = tid & 63, wid = tid >> 6;
  const float u0 = consts[2 + 2 * H + lane], u1 = consts[2 + 2 * H + lane + 64];
  const float c0 = consts[2 + 3 * H + lane], c1 = consts[2 + 3 * H + lane + 64];
  const int rs = rowb[blockIdx.x], re = rowb[blockIdx.x + 1];
  for (int base0 = rs + wid * 64; base0 < re; base0 += 1024) {
    const int i = base0 + lane;
    float av = 0.f;
    int sv = 0, dl = 0;
    if (i < re) {
      const ull pay = sp[i];
      const unsigned hi = (unsigned)(pay >> 32);
      av = __uint_as_float((unsigned)pay);
      sv = (int)(hi & 0xFFFFu);
      dl = (int)((hi >> 16) & 255u);
    }
    const int cnt = min(64, re - base0);
    for (int j = 0; j < cnt; ++j) {
      const int s = __shfl(sv, j, 64);
      const float a = __shfl(av, j, 64);
      const int d = __shfl(dl, j, 64);
      const float h0 = bf2f(h2b[(size_t)s * H + lane]);
      const float h1 = bf2f(h2b[(size_t)s * H + lane + 64]);
      atomicAdd(&agg[d * H + lane],      fmaxf(h0 + fmaf(a, u0, c0), 0.f));
      atomicAdd(&agg[d * H + lane + 64], fmaxf(h1 + fmaf(a, u1, c1), 0.f));
    }
  }
  __syncthreads();
  for (int idx = tid; idx < 256 * H; idx += 1024) {
    const int nn = idx >> 7, k = idx & (H - 1);
    const int n = (blockIdx.x << 8) + nn;
    if (n < N) t3[(size_t)n * H + k] = bf2f(h2b[(size_t)n * H + k]) + agg[idx];
  }
}

// h2b = bf16(t2 @ n2w + n2b)
__global__ __launch_bounds__(256) void mlp2_kernel(
    const float* __restrict__ t2, unsigned short* __restrict__ h2b,
    const float* __restrict__ n2w, const float* __restrict__ n2b, int N) {
  __shared__ float W[H * H];
  __shared__ float t[32][H];
  const int tid = threadIdx.x;
  for (int i = tid; i < H * H; i += 256) W[i] = n2w[i];
  const int kv = tid & 31;
  const int ng = tid >> 5;
  const float4* W4 = (const float4*)W;
  const float4 bias = ((const float4*)n2b)[kv];
  for (int tile = blockIdx.x * 32; tile < N; tile += gridDim.x * 32) {
    __syncthreads();
    const int nmax = min(32, N - tile);
    for (int i = tid; i < nmax * 32; i += 256) {
      const int nn = i >> 5, j4 = i & 31;
      ((float4*)&t[nn][0])[j4] = ((const float4*)(t2 + (size_t)(tile + nn) * H))[j4];
    }
    __syncthreads();
    float4 acc[4];
    acc[0] = acc[1] = acc[2] = acc[3] = make_float4(0.f, 0.f, 0.f, 0.f);
    for (int j = 0; j < H; j += 4) {
      const float4 w0 = W4[(j + 0) * 32 + kv];
      const float4 w1 = W4[(j + 1) * 32 + kv];
      const float4 w2 = W4[(j + 2) * 32 + kv];
      const float4 w3 = W4[(j + 3) * 32 + kv];
#pragma unroll
      for (int m = 0; m < 4; ++m) {
        const float4 tm = *(const float4*)&t[4 * ng + m][j];
        acc[m] = f4fma(tm.x, w0, acc[m]);
        acc[m] = f4fma(tm.y, w1, acc[m]);
        acc[m] = f4fma(tm.z, w2, acc[m]);
        acc[m] = f4fma(tm.w, w3, acc[m]);
      }
    }
#pragma unroll
    for (int m = 0; m < 4; ++m) {
      const int nn = 4 * ng + m;
      if (nn < nmax) {
        uint2 st;
        st.x = bf16pair(acc[m].x + bias.x, acc[m].y + bias.y);
        st.y = bf16pair(acc[m].z + bias.z, acc[m].w + bias.w);
        ((uint2*)(h2b + (size_t)(tile + nn) * H))[kv] = st;
      }
    }
  }
}

// h3 = t3 @ n3w + n3b; p[n]=h3.dec_w[:128]; q[n]=h3.dec_w[128:]
__global__ __launch_bounds__(256) void mlp3_kernel(
    const float* __restrict__ t3, const float* __restrict__ n3w,
    const float* __restrict__ n3b, const float* __restrict__ dec_w,
    float* __restrict__ p, float* __restrict__ q, int N) {
  __shared__ float W[H * H];
  __shared__ float t[32][H];
  const int tid = threadIdx.x;
  for (int i = tid; i < H * H; i += 256) W[i] = n3w[i];
  const int kv = tid & 31;
  const int ng = tid >> 5;
  const float4* W4 = (const float4*)W;
  const float4 bias = ((const float4*)n3b)[kv];
  const float4 dwA = ((const float4*)dec_w)[kv];
  const float4 dwB = ((const float4*)(dec_w + H))[kv];
  for (int tile = blockIdx.x * 32; tile < N; tile += gridDim.x * 32) {
    __syncthreads();
    const int nmax = min(32, N - tile);
    for (int i = tid; i < nmax * 32; i += 256) {
      const int nn = i >> 5, j4 = i & 31;
      ((float4*)&t[nn][0])[j4] = ((const float4*)(t3 + (size_t)(tile + nn) * H))[j4];
    }
    __syncthreads();
    float4 acc[4];
    acc[0] = acc[1] = acc[2] = acc[3] = make_float4(0.f, 0.f, 0.f, 0.f);
    for (int j = 0; j < H; j += 4) {
      const float4 w0 = W4[(j + 0) * 32 + kv];
      const float4 w1 = W4[(j + 1) * 32 + kv];
      const float4 w2 = W4[(j + 2) * 32 + kv];
      const float4 w3 = W4[(j + 3) * 32 + kv];
#pragma unroll
      for (int m = 0; m < 4; ++m) {
        const float4 tm = *(const float4*)&t[4 * ng + m][j];
        acc[m] = f4fma(tm.x, w0, acc[m]);
        acc[m] = f4fma(tm.y, w1, acc[m]);
        acc[m] = f4fma(tm.z, w2, acc[m]);
        acc[m] = f4fma(tm.w, w3, acc[m]);
      }
    }
#pragma unroll
    for (int m = 0; m < 4; ++m) {
      float4 h;
      h.x = acc[m].x + bias.x; h.y = acc[m].y + bias.y;
      h.z = acc[m].z + bias.z; h.w = acc[m].w + bias.w;
      float pd = h.x * dwA.x + h.y * dwA.y + h.z * dwA.z + h.w * dwA.w;
      float qd = h.x * dwB.x + h.y * dwB.y + h.z * dwB.z + h.w * dwB.w;
#pragma unroll
      for (int o = 16; o >= 1; o >>= 1) {
        pd += __shfl_xor(pd, o, 64);
        qd += __shfl_xor(qd, o, 64);
      }
      const int n = tile + 4 * ng + m;
      if (kv == 0 && 4 * ng + m < nmax) { p[n] = pd; q[n] = qd; }
    }
  }
}

__global__ void final_kernel(const int* __restrict__ src,
                             const int* __restrict__ dst,
                             const float* __restrict__ p,
                             const float* __restrict__ q,
                             const float* __restrict__ dec_b,
                             float* __restrict__ out, int E) {
  const int e = blockIdx.x * blockDim.x + threadIdx.x;
  if (e < E) out[e] = p[src[e]] + q[dst[e]] + dec_b[0];
}

extern "C" void kernel_launch(void* const* d_in, const int* in_sizes, int n_in,
                              void* d_out, int out_size, void* d_ws, size_t ws_size,
                              hipStream_t stream) {
  const float* x     = (const float*)d_in[0];
  const int*   ei    = (const int*)d_in[1];
  const float* ea    = (const float*)d_in[2];
  const float* em_w  = (const float*)d_in[3];
  const float* em_b  = (const float*)d_in[4];
  const float* l1_w  = (const float*)d_in[5];
  const float* l1_b  = (const float*)d_in[6];
  const float* n1_w  = (const float*)d_in[7];
  const float* n1_b  = (const float*)d_in[8];
  const float* l2_w  = (const float*)d_in[9];
  const float* l2_b  = (const float*)d_in[10];
  const float* n2_w  = (const float*)d_in[11];
  const float* n2_b  = (const float*)d_in[12];
  const float* l3_w  = (const float*)d_in[13];
  const float* l3_b  = (const float*)d_in[14];
  const float* n3_w  = (const float*)d_in[15];
  const float* n3_b  = (const float*)d_in[16];
  const float* dec_w = (const float*)d_in[17];
  const float* dec_b = (const float*)d_in[18];
  float* out = (float*)d_out;

  const int N = in_sizes[0];
  const int E = in_sizes[2];
  const int* src = ei;
  const int* dst = ei + E;

  float* ws       = (float*)d_ws;
  float* consts   = ws;                              // 1024 f
  ull*   sp       = (ull*)(ws + 1024);               // E u64 (8B aligned)
  float* bufA     = (float*)(sp + E);                // N*H f (t2, then t3)
  unsigned short* h2b = (unsigned short*)(bufA + (size_t)N * H);  // N*H bf16
  float* s1       = (float*)(h2b + (size_t)N * H);
  float* p        = s1 + N;
  float* q        = p + N;
  int*   bhist    = (int*)(q + N);                   // 256
  int*   rowb     = bhist + 256;                     // NBUCK+1
  int*   cursor   = rowb + 257;                      // NBUCK

  const int NBUCK = (N + 255) >> 8;                  // 196
  const int NBATCH = (E + 4095) >> 12;               // 196

  init_kernel<<<(N + 255) / 256 + 1, 256, 0, stream>>>(
      x, s1, bhist, N, em_w, em_b, l1_w, l1_b, l2_w, l2_b, n1_b,
      l3_w, l3_b, consts);
  bucket_hist<<<256, 256, 0, stream>>>(dst, bhist, E);
  bucket_scan<<<1, 256, 0, stream>>>(bhist, rowb, cursor, NBUCK);
  bin_scatter<<<NBATCH, 1024, 0, stream>>>(src, dst, ea, x, consts, cursor,
                                           sp, s1, E, NBUCK);
  agg2_kernel<<<NBUCK, 1024, 0, stream>>>(rowb, sp, s1, n1_w, n1_b, consts,
                                          bufA, N);
  mlp2_kernel<<<512, 256, 0, stream>>>(bufA, h2b, n2_w, n2_b, N);
  agg3_kernel<<<NBUCK, 1024, 0, stream>>>(rowb, sp, h2b, consts, bufA, N);
  mlp3_kernel<<<512, 256, 0, stream>>>(bufA, n3_w, n3_b, dec_w, p, q, N);
  final_kernel<<<(E + 255) / 256, 256, 0, stream>>>(src, dst, p, q, dec_b, out, E);
}

// Round 7
// 313.551 us; speedup vs baseline: 5.4420x; 5.4420x over previous
//
#include <hip/hip_runtime.h>

#define H 128

// ---------------------------------------------------------------------------
// R6 = R3 (proven 335us) with the CSR build replaced by a locality-aware
// two-phase counting sort:
//   A) bin_scatter: multisplit into 196 coarse buckets (256 nodes each);
//      per-(bucket,batch) contiguous runs -> ~2x write amp (was 9x).
//      Layer-1 scalar aggregation fused in.
//   B) fine_scatter: one block per bucket; LDS 256-node hist + scan ->
//      rowstart (coalesced) + within-region permutation (block-owned lines).
// Edge/MLP kernels are R3's verbatim. t3 reuses bufA (t2 dead after mlp2).
//
// Workspace (4-byte words):
//   consts[1024] | spc[E] u64 | spf[E] int2 | bufA[N*H] | h2b[N*H bf16]
//   | s1[N] | p[N] | q[N] | bhist[256] | rowb[257] | cursor[256]
//   | rowstart[NBUCK*256+1]
// Requires N <= 65536 (src packed in 16 bits). N = 50000.
// ---------------------------------------------------------------------------

typedef unsigned long long ull;

__device__ __forceinline__ float4 f4fma(float s, float4 w, float4 a) {
  a.x = fmaf(s, w.x, a.x); a.y = fmaf(s, w.y, a.y);
  a.z = fmaf(s, w.z, a.z); a.w = fmaf(s, w.w, a.w);
  return a;
}

__device__ __forceinline__ float bf2f(unsigned short v) {
  return __uint_as_float(((unsigned)v) << 16);
}

__device__ __forceinline__ unsigned bf16pair(float a, float b) {
  unsigned ua = __float_as_uint(a), ub = __float_as_uint(b);
  ua = (ua + 0x7FFFu + ((ua >> 16) & 1u)) >> 16;   // RNE
  ub = (ub + 0x7FFFu + ((ub >> 16) & 1u)) >> 16;
  return (ua & 0xFFFFu) | (ub << 16);
}

// blocks 0..NB-1: s1 = x (block 0 zeroes bhist); last block: folded consts
__global__ void init_kernel(
    const float* __restrict__ x, float* __restrict__ s1,
    int* __restrict__ bhist, int N,
    const float* __restrict__ em_w, const float* __restrict__ em_b,
    const float* __restrict__ l1_w, const float* __restrict__ l1_b,
    const float* __restrict__ l2_w, const float* __restrict__ l2_b,
    const float* __restrict__ n1_b,
    const float* __restrict__ l3_w, const float* __restrict__ l3_b,
    float* __restrict__ consts) {
  if (blockIdx.x == gridDim.x - 1) {
    const int k = threadIdx.x;
    __shared__ float sa[H], sc[H];
    if (k < H) {
      float u2 = 0.f, c2 = 0.f, u3 = 0.f, c3 = 0.f;
      for (int j = 0; j < H; ++j) {
        const float ew = em_w[j], eb = em_b[j];
        u2 = fmaf(ew, l2_w[j * H + k], u2);
        c2 = fmaf(eb, l2_w[j * H + k], c2);
        u3 = fmaf(ew, l3_w[j * H + k], u3);
        c3 = fmaf(eb, l3_w[j * H + k], c3);
      }
      consts[2 + k]         = u2;
      consts[2 + H + k]     = c2 + l2_b[k] + n1_b[k];
      consts[2 + 2 * H + k] = u3;
      consts[2 + 3 * H + k] = c3 + l3_b[k];
      sa[k] = em_w[k] * l1_w[k];
      sc[k] = em_b[k] * l1_w[k];
    }
    __syncthreads();
    for (int s = 64; s > 0; s >>= 1) {
      if (k < s) { sa[k] += sa[k + s]; sc[k] += sc[k + s]; }
      __syncthreads();
    }
    if (k == 0) { consts[0] = sa[0]; consts[1] = sc[0] + l1_b[0]; }
  } else {
    const int n = blockIdx.x * blockDim.x + threadIdx.x;
    if (n < N) s1[n] = x[n];
    if (blockIdx.x == 0) bhist[threadIdx.x] = 0;
  }
}

// coarse histogram of dst>>8 (LDS-combined)
__global__ __launch_bounds__(256) void bucket_hist(
    const int* __restrict__ dst, int* __restrict__ bhist, int E) {
  __shared__ int lh[256];
  const int tid = threadIdx.x;
  lh[tid] = 0;
  __syncthreads();
  const int stride = gridDim.x * blockDim.x;
  for (int e = blockIdx.x * blockDim.x + tid; e < E; e += stride)
    atomicAdd(&lh[dst[e] >> 8], 1);
  __syncthreads();
  if (lh[tid]) atomicAdd(&bhist[tid], lh[tid]);
}

// scan <=256 bucket counts; rowb = bucket offsets, cursor = coarse cursors
__global__ __launch_bounds__(256) void bucket_scan(
    const int* __restrict__ bhist, int* __restrict__ rowb,
    int* __restrict__ cursor, int NBUCK) {
  __shared__ int sd[256];
  const int tid = threadIdx.x;
  const int v = (tid < NBUCK) ? bhist[tid] : 0;
  sd[tid] = v;
  __syncthreads();
  for (int off = 1; off < 256; off <<= 1) {
    const int t = (tid >= off) ? sd[tid - off] : 0;
    __syncthreads();
    sd[tid] += t;
    __syncthreads();
  }
  if (tid < NBUCK) { rowb[tid] = sd[tid] - v; cursor[tid] = sd[tid] - v; }
  if (tid == 255) rowb[NBUCK] = sd[255];
}

// phase A: block-synchronous multisplit into coarse buckets; contiguous
// per-(bucket,batch) runs. Fused layer-1 scalar aggregation into s1.
// payload u64: hi = src | (dst&255)<<16, lo = ea bits
__global__ __launch_bounds__(1024) void bin_scatter(
    const int* __restrict__ src, const int* __restrict__ dst,
    const float* __restrict__ ea, const float* __restrict__ x,
    const float* __restrict__ consts, int* __restrict__ cursor,
    ull* __restrict__ spc, float* __restrict__ s1, int E, int NBUCK) {
  __shared__ int lhist[256];
  __shared__ int lbase[256];
  const int tid = threadIdx.x;
  const int base = blockIdx.x * 4096 + tid * 4;
  if (tid < 256) lhist[tid] = 0;
  __syncthreads();
  int s_[4], d_[4], b_[4], r_[4];
  float a_[4];
#pragma unroll
  for (int j = 0; j < 4; ++j) {
    const int e = base + j;
    if (e < E) {
      s_[j] = src[e]; d_[j] = dst[e]; a_[j] = ea[e];
      b_[j] = d_[j] >> 8;
      r_[j] = atomicAdd(&lhist[b_[j]], 1);
    } else {
      b_[j] = -1;
    }
  }
  __syncthreads();
  if (tid < NBUCK && lhist[tid] > 0)
    lbase[tid] = atomicAdd(&cursor[tid], lhist[tid]);
  __syncthreads();
  const float a1 = consts[0], c1 = consts[1];
#pragma unroll
  for (int j = 0; j < 4; ++j) {
    if (b_[j] >= 0) {
      const int pos = lbase[b_[j]] + r_[j];
      spc[pos] = ((ull)(unsigned)(s_[j] | ((d_[j] & 255) << 16)) << 32) |
                 (ull)(unsigned)__float_as_uint(a_[j]);
      const float m = fmaxf(x[s_[j]] + fmaf(a1, a_[j], c1), 0.f);
      unsafeAtomicAdd(&s1[d_[j]], m);
    }
  }
}

// phase B: one block per bucket. LDS 256-node hist -> scan -> rowstart
// (coalesced) + within-region permutation into final int2 array.
__global__ __launch_bounds__(1024) void fine_scatter(
    const int* __restrict__ rowb, const ull* __restrict__ spc,
    int2* __restrict__ spf, int* __restrict__ rowstart) {
  __shared__ int lh[256];
  __shared__ int sd[256];
  __shared__ int cur[256];
  const int tid = threadIdx.x;
  const int b = blockIdx.x;
  if (tid < 256) lh[tid] = 0;
  __syncthreads();
  const int rs = rowb[b], re = rowb[b + 1];
  for (int i = rs + tid; i < re; i += 1024)
    atomicAdd(&lh[(int)((spc[i] >> 48) & 255u)], 1);
  __syncthreads();
  if (tid < 256) sd[tid] = lh[tid];
  __syncthreads();
  for (int off = 1; off < 256; off <<= 1) {
    int t = 0;
    if (tid < 256 && tid >= off) t = sd[tid - off];
    __syncthreads();
    if (tid < 256) sd[tid] += t;
    __syncthreads();
  }
  if (tid < 256) {
    const int ex = rs + sd[tid] - lh[tid];   // exclusive + bucket base
    cur[tid] = ex;
    rowstart[(b << 8) + tid] = ex;
  }
  __syncthreads();
  for (int i = rs + tid; i < re; i += 1024) {
    const ull pay = spc[i];
    const int dl = (int)((pay >> 48) & 255u);
    const int pos = atomicAdd(&cur[dl], 1);
    spf[pos] = make_int2((int)((pay >> 32) & 0xFFFFu), (int)(unsigned)pay);
  }
}

// ------------------------- layer 2 (R3 verbatim) -------------------------
__global__ __launch_bounds__(256) void edge2_csr(
    const int* __restrict__ rowstart, const int2* __restrict__ sp,
    const float* __restrict__ s1, const float* __restrict__ n1w,
    const float* __restrict__ n1b, const float* __restrict__ consts,
    float* __restrict__ t2, int N) {
  const int n = (blockIdx.x * blockDim.x + threadIdx.x) >> 6;
  const int lane = threadIdx.x & 63;
  if (n >= N) return;
  const int rs = rowstart[n], re = rowstart[n + 1];
  const float w0 = n1w[lane],            w1 = n1w[lane + 64];
  const float u0 = consts[2 + lane],     u1 = consts[2 + lane + 64];
  const float c0 = consts[2 + H + lane], c1 = consts[2 + H + lane + 64];
  float acc0 = 0.f, acc1 = 0.f;
  for (int base = rs; base < re; base += 64) {
    const int i = base + lane;
    float s1v = 0.f, eav = 0.f;
    if (i < re) {
      const int2 sv = sp[i];
      s1v = s1[sv.x];
      eav = __int_as_float(sv.y);
    }
    const int cnt = min(64, re - base);
    for (int j = 0; j < cnt; ++j) {
      const float s = __shfl(s1v, j, 64);
      const float a = __shfl(eav, j, 64);
      acc0 += fmaxf(fmaf(s, w0, fmaf(a, u0, c0)), 0.f);
      acc1 += fmaxf(fmaf(s, w1, fmaf(a, u1, c1)), 0.f);
    }
  }
  const float sn = s1[n];
  t2[(size_t)n * H + lane]      = fmaf(sn, w0, n1b[lane])      + acc0;
  t2[(size_t)n * H + lane + 64] = fmaf(sn, w1, n1b[lane + 64]) + acc1;
}

// ------------------------- layer 3 (R3 verbatim) -------------------------
__global__ __launch_bounds__(256) void edge3_csr(
    const int* __restrict__ rowstart, const int2* __restrict__ sp,
    const unsigned short* __restrict__ h2b, const float* __restrict__ consts,
    float* __restrict__ t3, int N) {
  const int n = (blockIdx.x * blockDim.x + threadIdx.x) >> 6;
  const int lane = threadIdx.x & 63;
  if (n >= N) return;
  const int rs = rowstart[n], re = rowstart[n + 1];
  const int k0 = 2 * lane;
  const float u0 = consts[2 + 2 * H + k0], u1 = consts[2 + 2 * H + k0 + 1];
  const float c0 = consts[2 + 3 * H + k0], c1 = consts[2 + 3 * H + k0 + 1];
  float acc0 = 0.f, acc1 = 0.f;
  int i = rs;
  for (; i + 4 <= re; i += 4) {
    const int2 e0 = sp[i], e1 = sp[i + 1], e2 = sp[i + 2], e3 = sp[i + 3];
    const ushort2 h0 = *(const ushort2*)&h2b[(size_t)e0.x * H + k0];
    const ushort2 h1 = *(const ushort2*)&h2b[(size_t)e1.x * H + k0];
    const ushort2 h2v = *(const ushort2*)&h2b[(size_t)e2.x * H + k0];
    const ushort2 h3 = *(const ushort2*)&h2b[(size_t)e3.x * H + k0];
    const float a0 = __int_as_float(e0.y), a1 = __int_as_float(e1.y);
    const float a2 = __int_as_float(e2.y), a3 = __int_as_float(e3.y);
    acc0 += fmaxf(bf2f(h0.x) + fmaf(a0, u0, c0), 0.f);
    acc1 += fmaxf(bf2f(h0.y) + fmaf(a0, u1, c1), 0.f);
    acc0 += fmaxf(bf2f(h1.x) + fmaf(a1, u0, c0), 0.f);
    acc1 += fmaxf(bf2f(h1.y) + fmaf(a1, u1, c1), 0.f);
    acc0 += fmaxf(bf2f(h2v.x) + fmaf(a2, u0, c0), 0.f);
    acc1 += fmaxf(bf2f(h2v.y) + fmaf(a2, u1, c1), 0.f);
    acc0 += fmaxf(bf2f(h3.x) + fmaf(a3, u0, c0), 0.f);
    acc1 += fmaxf(bf2f(h3.y) + fmaf(a3, u1, c1), 0.f);
  }
  for (; i < re; ++i) {
    const int2 ev = sp[i];
    const ushort2 hv = *(const ushort2*)&h2b[(size_t)ev.x * H + k0];
    const float a = __int_as_float(ev.y);
    acc0 += fmaxf(bf2f(hv.x) + fmaf(a, u0, c0), 0.f);
    acc1 += fmaxf(bf2f(hv.y) + fmaf(a, u1, c1), 0.f);
  }
  const ushort2 hn = *(const ushort2*)&h2b[(size_t)n * H + k0];
  float2 o;
  o.x = bf2f(hn.x) + acc0;
  o.y = bf2f(hn.y) + acc1;
  *(float2*)&t3[(size_t)n * H + k0] = o;
}

// ------------------------- node MLPs (R3 verbatim) -------------------------
__global__ __launch_bounds__(256) void mlp2_kernel(
    const float* __restrict__ t2, unsigned short* __restrict__ h2b,
    const float* __restrict__ n2w, const float* __restrict__ n2b, int N) {
  __shared__ float W[H * H];
  __shared__ float t[32][H];
  const int tid = threadIdx.x;
  for (int i = tid; i < H * H; i += 256) W[i] = n2w[i];
  const int kv = tid & 31;
  const int ng = tid >> 5;
  const float4* W4 = (const float4*)W;
  const float4 bias = ((const float4*)n2b)[kv];
  for (int tile = blockIdx.x * 32; tile < N; tile += gridDim.x * 32) {
    __syncthreads();
    const int nmax = min(32, N - tile);
    for (int i = tid; i < nmax * 32; i += 256) {
      const int nn = i >> 5, j4 = i & 31;
      ((float4*)&t[nn][0])[j4] = ((const float4*)(t2 + (size_t)(tile + nn) * H))[j4];
    }
    __syncthreads();
    float4 acc[4];
    acc[0] = acc[1] = acc[2] = acc[3] = make_float4(0.f, 0.f, 0.f, 0.f);
    for (int j = 0; j < H; j += 4) {
      const float4 w0 = W4[(j + 0) * 32 + kv];
      const float4 w1 = W4[(j + 1) * 32 + kv];
      const float4 w2 = W4[(j + 2) * 32 + kv];
      const float4 w3 = W4[(j + 3) * 32 + kv];
#pragma unroll
      for (int m = 0; m < 4; ++m) {
        const float4 tm = *(const float4*)&t[4 * ng + m][j];
        acc[m] = f4fma(tm.x, w0, acc[m]);
        acc[m] = f4fma(tm.y, w1, acc[m]);
        acc[m] = f4fma(tm.z, w2, acc[m]);
        acc[m] = f4fma(tm.w, w3, acc[m]);
      }
    }
#pragma unroll
    for (int m = 0; m < 4; ++m) {
      const int nn = 4 * ng + m;
      if (nn < nmax) {
        uint2 st;
        st.x = bf16pair(acc[m].x + bias.x, acc[m].y + bias.y);
        st.y = bf16pair(acc[m].z + bias.z, acc[m].w + bias.w);
        ((uint2*)(h2b + (size_t)(tile + nn) * H))[kv] = st;
      }
    }
  }
}

__global__ __launch_bounds__(256) void mlp3_kernel(
    const float* __restrict__ t3, const float* __restrict__ n3w,
    const float* __restrict__ n3b, const float* __restrict__ dec_w,
    float* __restrict__ p, float* __restrict__ q, int N) {
  __shared__ float W[H * H];
  __shared__ float t[32][H];
  const int tid = threadIdx.x;
  for (int i = tid; i < H * H; i += 256) W[i] = n3w[i];
  const int kv = tid & 31;
  const int ng = tid >> 5;
  const float4* W4 = (const float4*)W;
  const float4 bias = ((const float4*)n3b)[kv];
  const float4 dwA = ((const float4*)dec_w)[kv];
  const float4 dwB = ((const float4*)(dec_w + H))[kv];
  for (int tile = blockIdx.x * 32; tile < N; tile += gridDim.x * 32) {
    __syncthreads();
    const int nmax = min(32, N - tile);
    for (int i = tid; i < nmax * 32; i += 256) {
      const int nn = i >> 5, j4 = i & 31;
      ((float4*)&t[nn][0])[j4] = ((const float4*)(t3 + (size_t)(tile + nn) * H))[j4];
    }
    __syncthreads();
    float4 acc[4];
    acc[0] = acc[1] = acc[2] = acc[3] = make_float4(0.f, 0.f, 0.f, 0.f);
    for (int j = 0; j < H; j += 4) {
      const float4 w0 = W4[(j + 0) * 32 + kv];
      const float4 w1 = W4[(j + 1) * 32 + kv];
      const float4 w2 = W4[(j + 2) * 32 + kv];
      const float4 w3 = W4[(j + 3) * 32 + kv];
#pragma unroll
      for (int m = 0; m < 4; ++m) {
        const float4 tm = *(const float4*)&t[4 * ng + m][j];
        acc[m] = f4fma(tm.x, w0, acc[m]);
        acc[m] = f4fma(tm.y, w1, acc[m]);
        acc[m] = f4fma(tm.z, w2, acc[m]);
        acc[m] = f4fma(tm.w, w3, acc[m]);
      }
    }
#pragma unroll
    for (int m = 0; m < 4; ++m) {
      float4 h;
      h.x = acc[m].x + bias.x; h.y = acc[m].y + bias.y;
      h.z = acc[m].z + bias.z; h.w = acc[m].w + bias.w;
      float pd = h.x * dwA.x + h.y * dwA.y + h.z * dwA.z + h.w * dwA.w;
      float qd = h.x * dwB.x + h.y * dwB.y + h.z * dwB.z + h.w * dwB.w;
#pragma unroll
      for (int o = 16; o >= 1; o >>= 1) {
        pd += __shfl_xor(pd, o, 64);
        qd += __shfl_xor(qd, o, 64);
      }
      const int n = tile + 4 * ng + m;
      if (kv == 0 && 4 * ng + m < nmax) { p[n] = pd; q[n] = qd; }
    }
  }
}

__global__ void final_kernel(const int* __restrict__ src,
                             const int* __restrict__ dst,
                             const float* __restrict__ p,
                             const float* __restrict__ q,
                             const float* __restrict__ dec_b,
                             float* __restrict__ out, int E) {
  const int e = blockIdx.x * blockDim.x + threadIdx.x;
  if (e < E) out[e] = p[src[e]] + q[dst[e]] + dec_b[0];
}

extern "C" void kernel_launch(void* const* d_in, const int* in_sizes, int n_in,
                              void* d_out, int out_size, void* d_ws, size_t ws_size,
                              hipStream_t stream) {
  const float* x     = (const float*)d_in[0];
  const int*   ei    = (const int*)d_in[1];
  const float* ea    = (const float*)d_in[2];
  const float* em_w  = (const float*)d_in[3];
  const float* em_b  = (const float*)d_in[4];
  const float* l1_w  = (const float*)d_in[5];
  const float* l1_b  = (const float*)d_in[6];
  const float* n1_w  = (const float*)d_in[7];
  const float* n1_b  = (const float*)d_in[8];
  const float* l2_w  = (const float*)d_in[9];
  const float* l2_b  = (const float*)d_in[10];
  const float* n2_w  = (const float*)d_in[11];
  const float* n2_b  = (const float*)d_in[12];
  const float* l3_w  = (const float*)d_in[13];
  const float* l3_b  = (const float*)d_in[14];
  const float* n3_w  = (const float*)d_in[15];
  const float* n3_b  = (const float*)d_in[16];
  const float* dec_w = (const float*)d_in[17];
  const float* dec_b = (const float*)d_in[18];
  float* out = (float*)d_out;

  const int N = in_sizes[0];
  const int E = in_sizes[2];
  const int* src = ei;
  const int* dst = ei + E;

  const int NBUCK = (N + 255) >> 8;                  // 196
  const int NBATCH = (E + 4095) >> 12;               // 196

  float* ws       = (float*)d_ws;
  float* consts   = ws;                              // 1024 f
  ull*   spc      = (ull*)(ws + 1024);               // E u64 (coarse)
  int2*  spf      = (int2*)(spc + E);                // E int2 (final CSR order)
  float* bufA     = (float*)(spf + E);               // N*H f (t2, then t3)
  unsigned short* h2b = (unsigned short*)(bufA + (size_t)N * H);  // N*H bf16
  float* s1       = (float*)(h2b + (size_t)N * H);
  float* p        = s1 + N;
  float* q        = p + N;
  int*   bhist    = (int*)(q + N);                   // 256
  int*   rowb     = bhist + 256;                     // NBUCK+1
  int*   cursor   = rowb + 257;                      // NBUCK
  int*   rowstart = cursor + 256;                    // NBUCK*256+1

  init_kernel<<<(N + 255) / 256 + 1, 256, 0, stream>>>(
      x, s1, bhist, N, em_w, em_b, l1_w, l1_b, l2_w, l2_b, n1_b,
      l3_w, l3_b, consts);
  bucket_hist<<<256, 256, 0, stream>>>(dst, bhist, E);
  bucket_scan<<<1, 256, 0, stream>>>(bhist, rowb, cursor, NBUCK);
  bin_scatter<<<NBATCH, 1024, 0, stream>>>(src, dst, ea, x, consts, cursor,
                                           spc, s1, E, NBUCK);
  fine_scatter<<<NBUCK, 1024, 0, stream>>>(rowb, spc, spf, rowstart);

  const int nwblocks = (N + 3) / 4;  // 4 waves (nodes) per 256-thread block
  edge2_csr<<<nwblocks, 256, 0, stream>>>(rowstart, spf, s1, n1_w, n1_b,
                                          consts, bufA, N);
  mlp2_kernel<<<512, 256, 0, stream>>>(bufA, h2b, n2_w, n2_b, N);
  edge3_csr<<<nwblocks, 256, 0, stream>>>(rowstart, spf, h2b, consts, bufA, N);
  mlp3_kernel<<<512, 256, 0, stream>>>(bufA, n3_w, n3_b, dec_w, p, q, N);
  final_kernel<<<(E + 255) / 256, 256, 0, stream>>>(src, dst, p, q, dec_b, out, E);
}

// Round 8
// 266.253 us; speedup vs baseline: 6.4087x; 1.1776x over previous
//
#include <hip/hip_runtime.h>

#define H 128
#define CAPC 5376   // per-bucket region capacity: mean 4096 + 20 sigma

// ---------------------------------------------------------------------------
// R7: R6 skeleton, rebuilt CSR construction:
//  - fixed-capacity per-bucket regions (CAP=5376) -> no global hist/scan
//  - bin_scatter: pure multisplit, 2 edges/thread, 391 blocks
//  - fine_scatter: permute in LDS -> coalesced spf write (amp 1.0), fused
//    layer-1 (s1) computed wave-per-node from LDS payload (no atomics)
//  - rowstart stored per-bucket at stride 257 (node ranges never cross
//    buckets, so re = rowstart[base+1] stays correct at bucket edges)
// Edge2/3 + MLPs verbatim from R3/R6 (proven). t3 reuses bufA.
//
// Workspace (4-byte words):
//   consts[1024] | spc[NBUCK*CAP] u64 | spf[NBUCK*CAP] int2 | bufA[N*H]
//   | h2b[N*H bf16] | s1[N] | p[N] | q[N] | cursor[256] | rowstart[NBUCK*257]
// Requires N <= 65536 (src packed in 16 bits). N = 50000.
// ---------------------------------------------------------------------------

typedef unsigned long long ull;

__device__ __forceinline__ float4 f4fma(float s, float4 w, float4 a) {
  a.x = fmaf(s, w.x, a.x); a.y = fmaf(s, w.y, a.y);
  a.z = fmaf(s, w.z, a.z); a.w = fmaf(s, w.w, a.w);
  return a;
}

__device__ __forceinline__ float bf2f(unsigned short v) {
  return __uint_as_float(((unsigned)v) << 16);
}

__device__ __forceinline__ unsigned bf16pair(float a, float b) {
  unsigned ua = __float_as_uint(a), ub = __float_as_uint(b);
  ua = (ua + 0x7FFFu + ((ua >> 16) & 1u)) >> 16;   // RNE
  ub = (ub + 0x7FFFu + ((ub >> 16) & 1u)) >> 16;
  return (ua & 0xFFFFu) | (ub << 16);
}

// one block: folded constants + zero bucket cursors
__global__ __launch_bounds__(256) void init_consts(
    const float* __restrict__ em_w, const float* __restrict__ em_b,
    const float* __restrict__ l1_w, const float* __restrict__ l1_b,
    const float* __restrict__ l2_w, const float* __restrict__ l2_b,
    const float* __restrict__ n1_b,
    const float* __restrict__ l3_w, const float* __restrict__ l3_b,
    float* __restrict__ consts, int* __restrict__ cursor, int NBUCK) {
  const int k = threadIdx.x;
  if (k < NBUCK) cursor[k] = 0;
  __shared__ float sa[H], sc[H];
  if (k < H) {
    float u2 = 0.f, c2 = 0.f, u3 = 0.f, c3 = 0.f;
    for (int j = 0; j < H; ++j) {
      const float ew = em_w[j], eb = em_b[j];
      u2 = fmaf(ew, l2_w[j * H + k], u2);
      c2 = fmaf(eb, l2_w[j * H + k], c2);
      u3 = fmaf(ew, l3_w[j * H + k], u3);
      c3 = fmaf(eb, l3_w[j * H + k], c3);
    }
    consts[2 + k]         = u2;
    consts[2 + H + k]     = c2 + l2_b[k] + n1_b[k];
    consts[2 + 2 * H + k] = u3;
    consts[2 + 3 * H + k] = c3 + l3_b[k];
    sa[k] = em_w[k] * l1_w[k];
    sc[k] = em_b[k] * l1_w[k];
  }
  __syncthreads();
  for (int s = 64; s > 0; s >>= 1) {
    if (k < s) { sa[k] += sa[k + s]; sc[k] += sc[k + s]; }
    __syncthreads();
  }
  if (k == 0) { consts[0] = sa[0]; consts[1] = sc[0] + l1_b[0]; }
}

// pure multisplit into fixed-capacity bucket regions; 2 edges per thread.
// payload u64: hi = src | (dst&255)<<16, lo = ea bits
__global__ __launch_bounds__(1024) void bin_scatter(
    const int* __restrict__ src, const int* __restrict__ dst,
    const float* __restrict__ ea, int* __restrict__ cursor,
    ull* __restrict__ spc, int E, int NBUCK) {
  __shared__ int lhist[256];
  __shared__ int lbase[256];
  const int tid = threadIdx.x;
  const int base = blockIdx.x * 2048 + tid * 2;
  if (tid < 256) lhist[tid] = 0;
  __syncthreads();
  int s_[2], d_[2], b_[2], r_[2];
  float a_[2];
#pragma unroll
  for (int j = 0; j < 2; ++j) {
    const int e = base + j;
    if (e < E) {
      s_[j] = src[e]; d_[j] = dst[e]; a_[j] = ea[e];
      b_[j] = d_[j] >> 8;
      r_[j] = atomicAdd(&lhist[b_[j]], 1);
    } else {
      b_[j] = -1;
    }
  }
  __syncthreads();
  if (tid < NBUCK && lhist[tid] > 0)
    lbase[tid] = atomicAdd(&cursor[tid], lhist[tid]);
  __syncthreads();
#pragma unroll
  for (int j = 0; j < 2; ++j) {
    if (b_[j] >= 0) {
      const int pl = lbase[b_[j]] + r_[j];
      if (pl < CAPC)   // impossible overflow guard (20 sigma)
        spc[(size_t)b_[j] * CAPC + pl] =
            ((ull)(unsigned)(s_[j] | ((d_[j] & 255) << 16)) << 32) |
            (ull)(unsigned)__float_as_uint(a_[j]);
    }
  }
}

// one block per bucket: LDS hist+scan -> permute into LDS -> coalesced spf
// write + rowstart; fused layer-1: s1[n] = x[n] + sum relu(x[src]+a1*ea+c1)
__global__ __launch_bounds__(1024) void fine_scatter(
    const int* __restrict__ cursor, const ull* __restrict__ spc,
    const float* __restrict__ x, const float* __restrict__ consts,
    int2* __restrict__ spf, int* __restrict__ rowstart,
    float* __restrict__ s1, int N) {
  __shared__ int lh[256];
  __shared__ int sd[256];
  __shared__ int cur[256];
  __shared__ int2 pay[CAPC];   // 43 KB
  const int tid = threadIdx.x;
  const int b = blockIdx.x;
  const int cnt = min(cursor[b], CAPC);
  const size_t rbase = (size_t)b * CAPC;
  if (tid < 256) lh[tid] = 0;
  __syncthreads();
  for (int i = tid; i < cnt; i += 1024)
    atomicAdd(&lh[(int)((spc[rbase + i] >> 48) & 255u)], 1);
  __syncthreads();
  if (tid < 256) sd[tid] = lh[tid];
  __syncthreads();
  for (int off = 1; off < 256; off <<= 1) {
    int t = 0;
    if (tid < 256 && tid >= off) t = sd[tid - off];
    __syncthreads();
    if (tid < 256) sd[tid] += t;
    __syncthreads();
  }
  if (tid < 256) {
    const int ex = sd[tid] - lh[tid];
    cur[tid] = ex;
    rowstart[b * 257 + tid] = (int)rbase + ex;
    if (tid == 0) rowstart[b * 257 + 256] = (int)rbase + cnt;
  }
  __syncthreads();
  for (int i = tid; i < cnt; i += 1024) {
    const ull payv = spc[rbase + i];
    const int dl = (int)((payv >> 48) & 255u);
    const int pos = atomicAdd(&cur[dl], 1);
    pay[pos] = make_int2((int)((payv >> 32) & 0xFFFFu), (int)(unsigned)payv);
  }
  __syncthreads();
  // coalesced write-out of permuted payload
  for (int i = tid; i < cnt; i += 1024) spf[rbase + i] = pay[i];
  // fused layer-1: wave per node from LDS payload
  const int lane = tid & 63, wid = tid >> 6;
  const float a1 = consts[0], c1 = consts[1];
  for (int i = wid; i < 256; i += 16) {
    const int n = (b << 8) + i;
    if (n >= N) break;
    const int rsl = sd[i] - lh[i], ci = lh[i];
    float part = 0.f;
    for (int j = lane; j < ci; j += 64) {
      const int2 pv = pay[rsl + j];
      part += fmaxf(x[pv.x] + fmaf(a1, __int_as_float(pv.y), c1), 0.f);
    }
#pragma unroll
    for (int o = 32; o >= 1; o >>= 1) part += __shfl_xor(part, o, 64);
    if (lane == 0) s1[n] = x[n] + part;
  }
}

// ------------------------- layer 2 (R3 verbatim + stride-257 rowstart) ------
__global__ __launch_bounds__(256) void edge2_csr(
    const int* __restrict__ rowstart, const int2* __restrict__ sp,
    const float* __restrict__ s1, const float* __restrict__ n1w,
    const float* __restrict__ n1b, const float* __restrict__ consts,
    float* __restrict__ t2, int N) {
  const int n = (blockIdx.x * blockDim.x + threadIdx.x) >> 6;
  const int lane = threadIdx.x & 63;
  if (n >= N) return;
  const int rbase = (n >> 8) * 257 + (n & 255);
  const int rs = rowstart[rbase], re = rowstart[rbase + 1];
  const float w0 = n1w[lane],            w1 = n1w[lane + 64];
  const float u0 = consts[2 + lane],     u1 = consts[2 + lane + 64];
  const float c0 = consts[2 + H + lane], c1 = consts[2 + H + lane + 64];
  float acc0 = 0.f, acc1 = 0.f;
  for (int base = rs; base < re; base += 64) {
    const int i = base + lane;
    float s1v = 0.f, eav = 0.f;
    if (i < re) {
      const int2 sv = sp[i];
      s1v = s1[sv.x];
      eav = __int_as_float(sv.y);
    }
    const int cnt = min(64, re - base);
    for (int j = 0; j < cnt; ++j) {
      const float s = __shfl(s1v, j, 64);
      const float a = __shfl(eav, j, 64);
      acc0 += fmaxf(fmaf(s, w0, fmaf(a, u0, c0)), 0.f);
      acc1 += fmaxf(fmaf(s, w1, fmaf(a, u1, c1)), 0.f);
    }
  }
  const float sn = s1[n];
  t2[(size_t)n * H + lane]      = fmaf(sn, w0, n1b[lane])      + acc0;
  t2[(size_t)n * H + lane + 64] = fmaf(sn, w1, n1b[lane + 64]) + acc1;
}

// ------------------------- layer 3 (R3 verbatim + stride-257 rowstart) ------
__global__ __launch_bounds__(256) void edge3_csr(
    const int* __restrict__ rowstart, const int2* __restrict__ sp,
    const unsigned short* __restrict__ h2b, const float* __restrict__ consts,
    float* __restrict__ t3, int N) {
  const int n = (blockIdx.x * blockDim.x + threadIdx.x) >> 6;
  const int lane = threadIdx.x & 63;
  if (n >= N) return;
  const int rbase = (n >> 8) * 257 + (n & 255);
  const int rs = rowstart[rbase], re = rowstart[rbase + 1];
  const int k0 = 2 * lane;
  const float u0 = consts[2 + 2 * H + k0], u1 = consts[2 + 2 * H + k0 + 1];
  const float c0 = consts[2 + 3 * H + k0], c1 = consts[2 + 3 * H + k0 + 1];
  float acc0 = 0.f, acc1 = 0.f;
  int i = rs;
  for (; i + 4 <= re; i += 4) {
    const int2 e0 = sp[i], e1 = sp[i + 1], e2 = sp[i + 2], e3 = sp[i + 3];
    const ushort2 h0 = *(const ushort2*)&h2b[(size_t)e0.x * H + k0];
    const ushort2 h1 = *(const ushort2*)&h2b[(size_t)e1.x * H + k0];
    const ushort2 h2v = *(const ushort2*)&h2b[(size_t)e2.x * H + k0];
    const ushort2 h3 = *(const ushort2*)&h2b[(size_t)e3.x * H + k0];
    const float a0 = __int_as_float(e0.y), a1 = __int_as_float(e1.y);
    const float a2 = __int_as_float(e2.y), a3 = __int_as_float(e3.y);
    acc0 += fmaxf(bf2f(h0.x) + fmaf(a0, u0, c0), 0.f);
    acc1 += fmaxf(bf2f(h0.y) + fmaf(a0, u1, c1), 0.f);
    acc0 += fmaxf(bf2f(h1.x) + fmaf(a1, u0, c0), 0.f);
    acc1 += fmaxf(bf2f(h1.y) + fmaf(a1, u1, c1), 0.f);
    acc0 += fmaxf(bf2f(h2v.x) + fmaf(a2, u0, c0), 0.f);
    acc1 += fmaxf(bf2f(h2v.y) + fmaf(a2, u1, c1), 0.f);
    acc0 += fmaxf(bf2f(h3.x) + fmaf(a3, u0, c0), 0.f);
    acc1 += fmaxf(bf2f(h3.y) + fmaf(a3, u1, c1), 0.f);
  }
  for (; i < re; ++i) {
    const int2 ev = sp[i];
    const ushort2 hv = *(const ushort2*)&h2b[(size_t)ev.x * H + k0];
    const float a = __int_as_float(ev.y);
    acc0 += fmaxf(bf2f(hv.x) + fmaf(a, u0, c0), 0.f);
    acc1 += fmaxf(bf2f(hv.y) + fmaf(a, u1, c1), 0.f);
  }
  const ushort2 hn = *(const ushort2*)&h2b[(size_t)n * H + k0];
  float2 o;
  o.x = bf2f(hn.x) + acc0;
  o.y = bf2f(hn.y) + acc1;
  *(float2*)&t3[(size_t)n * H + k0] = o;
}

// ------------------------- node MLPs (R3 verbatim) -------------------------
__global__ __launch_bounds__(256) void mlp2_kernel(
    const float* __restrict__ t2, unsigned short* __restrict__ h2b,
    const float* __restrict__ n2w, const float* __restrict__ n2b, int N) {
  __shared__ float W[H * H];
  __shared__ float t[32][H];
  const int tid = threadIdx.x;
  for (int i = tid; i < H * H; i += 256) W[i] = n2w[i];
  const int kv = tid & 31;
  const int ng = tid >> 5;
  const float4* W4 = (const float4*)W;
  const float4 bias = ((const float4*)n2b)[kv];
  for (int tile = blockIdx.x * 32; tile < N; tile += gridDim.x * 32) {
    __syncthreads();
    const int nmax = min(32, N - tile);
    for (int i = tid; i < nmax * 32; i += 256) {
      const int nn = i >> 5, j4 = i & 31;
      ((float4*)&t[nn][0])[j4] = ((const float4*)(t2 + (size_t)(tile + nn) * H))[j4];
    }
    __syncthreads();
    float4 acc[4];
    acc[0] = acc[1] = acc[2] = acc[3] = make_float4(0.f, 0.f, 0.f, 0.f);
    for (int j = 0; j < H; j += 4) {
      const float4 w0 = W4[(j + 0) * 32 + kv];
      const float4 w1 = W4[(j + 1) * 32 + kv];
      const float4 w2 = W4[(j + 2) * 32 + kv];
      const float4 w3 = W4[(j + 3) * 32 + kv];
#pragma unroll
      for (int m = 0; m < 4; ++m) {
        const float4 tm = *(const float4*)&t[4 * ng + m][j];
        acc[m] = f4fma(tm.x, w0, acc[m]);
        acc[m] = f4fma(tm.y, w1, acc[m]);
        acc[m] = f4fma(tm.z, w2, acc[m]);
        acc[m] = f4fma(tm.w, w3, acc[m]);
      }
    }
#pragma unroll
    for (int m = 0; m < 4; ++m) {
      const int nn = 4 * ng + m;
      if (nn < nmax) {
        uint2 st;
        st.x = bf16pair(acc[m].x + bias.x, acc[m].y + bias.y);
        st.y = bf16pair(acc[m].z + bias.z, acc[m].w + bias.w);
        ((uint2*)(h2b + (size_t)(tile + nn) * H))[kv] = st;
      }
    }
  }
}

__global__ __launch_bounds__(256) void mlp3_kernel(
    const float* __restrict__ t3, const float* __restrict__ n3w,
    const float* __restrict__ n3b, const float* __restrict__ dec_w,
    float* __restrict__ p, float* __restrict__ q, int N) {
  __shared__ float W[H * H];
  __shared__ float t[32][H];
  const int tid = threadIdx.x;
  for (int i = tid; i < H * H; i += 256) W[i] = n3w[i];
  const int kv = tid & 31;
  const int ng = tid >> 5;
  const float4* W4 = (const float4*)W;
  const float4 bias = ((const float4*)n3b)[kv];
  const float4 dwA = ((const float4*)dec_w)[kv];
  const float4 dwB = ((const float4*)(dec_w + H))[kv];
  for (int tile = blockIdx.x * 32; tile < N; tile += gridDim.x * 32) {
    __syncthreads();
    const int nmax = min(32, N - tile);
    for (int i = tid; i < nmax * 32; i += 256) {
      const int nn = i >> 5, j4 = i & 31;
      ((float4*)&t[nn][0])[j4] = ((const float4*)(t3 + (size_t)(tile + nn) * H))[j4];
    }
    __syncthreads();
    float4 acc[4];
    acc[0] = acc[1] = acc[2] = acc[3] = make_float4(0.f, 0.f, 0.f, 0.f);
    for (int j = 0; j < H; j += 4) {
      const float4 w0 = W4[(j + 0) * 32 + kv];
      const float4 w1 = W4[(j + 1) * 32 + kv];
      const float4 w2 = W4[(j + 2) * 32 + kv];
      const float4 w3 = W4[(j + 3) * 32 + kv];
#pragma unroll
      for (int m = 0; m < 4; ++m) {
        const float4 tm = *(const float4*)&t[4 * ng + m][j];
        acc[m] = f4fma(tm.x, w0, acc[m]);
        acc[m] = f4fma(tm.y, w1, acc[m]);
        acc[m] = f4fma(tm.z, w2, acc[m]);
        acc[m] = f4fma(tm.w, w3, acc[m]);
      }
    }
#pragma unroll
    for (int m = 0; m < 4; ++m) {
      float4 h;
      h.x = acc[m].x + bias.x; h.y = acc[m].y + bias.y;
      h.z = acc[m].z + bias.z; h.w = acc[m].w + bias.w;
      float pd = h.x * dwA.x + h.y * dwA.y + h.z * dwA.z + h.w * dwA.w;
      float qd = h.x * dwB.x + h.y * dwB.y + h.z * dwB.z + h.w * dwB.w;
#pragma unroll
      for (int o = 16; o >= 1; o >>= 1) {
        pd += __shfl_xor(pd, o, 64);
        qd += __shfl_xor(qd, o, 64);
      }
      const int n = tile + 4 * ng + m;
      if (kv == 0 && 4 * ng + m < nmax) { p[n] = pd; q[n] = qd; }
    }
  }
}

__global__ void final_kernel(const int* __restrict__ src,
                             const int* __restrict__ dst,
                             const float* __restrict__ p,
                             const float* __restrict__ q,
                             const float* __restrict__ dec_b,
                             float* __restrict__ out, int E) {
  const int e = blockIdx.x * blockDim.x + threadIdx.x;
  if (e < E) out[e] = p[src[e]] + q[dst[e]] + dec_b[0];
}

extern "C" void kernel_launch(void* const* d_in, const int* in_sizes, int n_in,
                              void* d_out, int out_size, void* d_ws, size_t ws_size,
                              hipStream_t stream) {
  const float* x     = (const float*)d_in[0];
  const int*   ei    = (const int*)d_in[1];
  const float* ea    = (const float*)d_in[2];
  const float* em_w  = (const float*)d_in[3];
  const float* em_b  = (const float*)d_in[4];
  const float* l1_w  = (const float*)d_in[5];
  const float* l1_b  = (const float*)d_in[6];
  const float* n1_w  = (const float*)d_in[7];
  const float* n1_b  = (const float*)d_in[8];
  const float* l2_w  = (const float*)d_in[9];
  const float* l2_b  = (const float*)d_in[10];
  const float* n2_w  = (const float*)d_in[11];
  const float* n2_b  = (const float*)d_in[12];
  const float* l3_w  = (const float*)d_in[13];
  const float* l3_b  = (const float*)d_in[14];
  const float* n3_w  = (const float*)d_in[15];
  const float* n3_b  = (const float*)d_in[16];
  const float* dec_w = (const float*)d_in[17];
  const float* dec_b = (const float*)d_in[18];
  float* out = (float*)d_out;

  const int N = in_sizes[0];
  const int E = in_sizes[2];
  const int* src = ei;
  const int* dst = ei + E;

  const int NBUCK = (N + 255) >> 8;                  // 196
  const int NBATCH = (E + 2047) >> 11;               // 391

  float* ws       = (float*)d_ws;
  float* consts   = ws;                              // 1024 f
  ull*   spc      = (ull*)(ws + 1024);               // NBUCK*CAP u64
  int2*  spf      = (int2*)(spc + (size_t)NBUCK * CAPC);  // NBUCK*CAP int2
  float* bufA     = (float*)(spf + (size_t)NBUCK * CAPC); // N*H f (t2 -> t3)
  unsigned short* h2b = (unsigned short*)(bufA + (size_t)N * H);  // N*H bf16
  float* s1       = (float*)(h2b + (size_t)N * H);
  float* p        = s1 + N;
  float* q        = p + N;
  int*   cursor   = (int*)(q + N);                   // 256
  int*   rowstart = cursor + 256;                    // NBUCK*257

  init_consts<<<1, 256, 0, stream>>>(em_w, em_b, l1_w, l1_b, l2_w, l2_b,
                                     n1_b, l3_w, l3_b, consts, cursor, NBUCK);
  bin_scatter<<<NBATCH, 1024, 0, stream>>>(src, dst, ea, cursor, spc, E, NBUCK);
  fine_scatter<<<NBUCK, 1024, 0, stream>>>(cursor, spc, x, consts, spf,
                                           rowstart, s1, N);

  const int nwblocks = (N + 3) / 4;  // 4 waves (nodes) per 256-thread block
  edge2_csr<<<nwblocks, 256, 0, stream>>>(rowstart, spf, s1, n1_w, n1_b,
                                          consts, bufA, N);
  mlp2_kernel<<<512, 256, 0, stream>>>(bufA, h2b, n2_w, n2_b, N);
  edge3_csr<<<nwblocks, 256, 0, stream>>>(rowstart, spf, h2b, consts, bufA, N);
  mlp3_kernel<<<512, 256, 0, stream>>>(bufA, n3_w, n3_b, dec_w, p, q, N);
  final_kernel<<<(E + 255) / 256, 256, 0, stream>>>(src, dst, p, q, dec_b, out, E);
}

// Round 9
// 246.671 us; speedup vs baseline: 6.9175x; 1.0794x over previous
//
#include <hip/hip_runtime.h>

#define H 128
#define CAPC 5376   // per-bucket region capacity: mean 4096 + 20 sigma

// ---------------------------------------------------------------------------
// R8 = R7 build + MFMA node-MLPs:
//  - t2/t3 stored bf16; W2/W3 pre-transposed to bf16 in GLOBAL (w2t/w3t,
//    32 KB each, L2-broadcast) -> B-fragments are contiguous 16B loads
//  - mlp2_mfma / mlp3_mfma: wave = 16 nodes x 128 outs via
//    v_mfma_f32_16x16x32_bf16 (A: m=lane&15,k=quad*8+j; D: col=lane&15,
//    row=quad*4+reg -- HW-verified layouts). mlp2 stages D in per-wave LDS
//    for coalesced stores; mlp3 stages h3 f32 and shfl-reduces decode dots.
//  - NPAD = ceil(N/64)*64 rows for t2b/t3b so overhang tiles read in-bounds
//    garbage (stores masked by n < N).
// Build (bin_scatter/fine_scatter), edge2/edge3 bodies, final: R7 proven.
// ---------------------------------------------------------------------------

typedef unsigned long long ull;
using bf16x8 = __attribute__((ext_vector_type(8))) short;
using f32x4  = __attribute__((ext_vector_type(4))) float;

__device__ __forceinline__ float bf2f(unsigned short v) {
  return __uint_as_float(((unsigned)v) << 16);
}
__device__ __forceinline__ unsigned short bf16r(float v) {
  unsigned u = __float_as_uint(v);
  u = (u + 0x7FFFu + ((u >> 16) & 1u)) >> 16;   // RNE
  return (unsigned short)u;
}
__device__ __forceinline__ unsigned bf16pair(float a, float b) {
  return (unsigned)bf16r(a) | ((unsigned)bf16r(b) << 16);
}

// block 0: folded consts + zero cursors; blocks 1..128: transpose W2,W3->bf16
__global__ __launch_bounds__(256) void init_consts(
    const float* __restrict__ em_w, const float* __restrict__ em_b,
    const float* __restrict__ l1_w, const float* __restrict__ l1_b,
    const float* __restrict__ l2_w, const float* __restrict__ l2_b,
    const float* __restrict__ n1_b,
    const float* __restrict__ l3_w, const float* __restrict__ l3_b,
    const float* __restrict__ n2w, const float* __restrict__ n3w,
    float* __restrict__ consts, int* __restrict__ cursor,
    unsigned short* __restrict__ w2t, unsigned short* __restrict__ w3t,
    int NBUCK) {
  if (blockIdx.x > 0) {
    const int i = (blockIdx.x - 1) * 256 + threadIdx.x;  // 0..32767
    if (i < H * H) {
      const int j = i >> 7, k = i & (H - 1);
      w2t[k * H + j] = bf16r(n2w[i]);
    } else {
      const int ii = i - H * H;
      const int j = ii >> 7, k = ii & (H - 1);
      w3t[k * H + j] = bf16r(n3w[ii]);
    }
    return;
  }
  const int k = threadIdx.x;
  if (k < NBUCK) cursor[k] = 0;
  __shared__ float sa[H], sc[H];
  if (k < H) {
    float u2 = 0.f, c2 = 0.f, u3 = 0.f, c3 = 0.f;
    for (int j = 0; j < H; ++j) {
      const float ew = em_w[j], eb = em_b[j];
      u2 = fmaf(ew, l2_w[j * H + k], u2);
      c2 = fmaf(eb, l2_w[j * H + k], c2);
      u3 = fmaf(ew, l3_w[j * H + k], u3);
      c3 = fmaf(eb, l3_w[j * H + k], c3);
    }
    consts[2 + k]         = u2;
    consts[2 + H + k]     = c2 + l2_b[k] + n1_b[k];
    consts[2 + 2 * H + k] = u3;
    consts[2 + 3 * H + k] = c3 + l3_b[k];
    sa[k] = em_w[k] * l1_w[k];
    sc[k] = em_b[k] * l1_w[k];
  }
  __syncthreads();
  for (int s = 64; s > 0; s >>= 1) {
    if (k < s) { sa[k] += sa[k + s]; sc[k] += sc[k + s]; }
    __syncthreads();
  }
  if (k == 0) { consts[0] = sa[0]; consts[1] = sc[0] + l1_b[0]; }
}

// pure multisplit into fixed-capacity bucket regions; 2 edges per thread.
__global__ __launch_bounds__(1024) void bin_scatter(
    const int* __restrict__ src, const int* __restrict__ dst,
    const float* __restrict__ ea, int* __restrict__ cursor,
    ull* __restrict__ spc, int E, int NBUCK) {
  __shared__ int lhist[256];
  __shared__ int lbase[256];
  const int tid = threadIdx.x;
  const int base = blockIdx.x * 2048 + tid * 2;
  if (tid < 256) lhist[tid] = 0;
  __syncthreads();
  int s_[2], d_[2], b_[2], r_[2];
  float a_[2];
#pragma unroll
  for (int j = 0; j < 2; ++j) {
    const int e = base + j;
    if (e < E) {
      s_[j] = src[e]; d_[j] = dst[e]; a_[j] = ea[e];
      b_[j] = d_[j] >> 8;
      r_[j] = atomicAdd(&lhist[b_[j]], 1);
    } else {
      b_[j] = -1;
    }
  }
  __syncthreads();
  if (tid < NBUCK && lhist[tid] > 0)
    lbase[tid] = atomicAdd(&cursor[tid], lhist[tid]);
  __syncthreads();
#pragma unroll
  for (int j = 0; j < 2; ++j) {
    if (b_[j] >= 0) {
      const int pl = lbase[b_[j]] + r_[j];
      if (pl < CAPC)
        spc[(size_t)b_[j] * CAPC + pl] =
            ((ull)(unsigned)(s_[j] | ((d_[j] & 255) << 16)) << 32) |
            (ull)(unsigned)__float_as_uint(a_[j]);
    }
  }
}

// one block per bucket: LDS hist+scan -> permute in LDS -> coalesced spf
// write + rowstart; fused layer-1: s1[n] = x[n] + sum relu(x[src]+a1*ea+c1)
__global__ __launch_bounds__(1024) void fine_scatter(
    const int* __restrict__ cursor, const ull* __restrict__ spc,
    const float* __restrict__ x, const float* __restrict__ consts,
    int2* __restrict__ spf, int* __restrict__ rowstart,
    float* __restrict__ s1, int N) {
  __shared__ int lh[256];
  __shared__ int sd[256];
  __shared__ int cur[256];
  __shared__ int2 pay[CAPC];   // 43 KB
  const int tid = threadIdx.x;
  const int b = blockIdx.x;
  const int cnt = min(cursor[b], CAPC);
  const size_t rbase = (size_t)b * CAPC;
  if (tid < 256) lh[tid] = 0;
  __syncthreads();
  for (int i = tid; i < cnt; i += 1024)
    atomicAdd(&lh[(int)((spc[rbase + i] >> 48) & 255u)], 1);
  __syncthreads();
  if (tid < 256) sd[tid] = lh[tid];
  __syncthreads();
  for (int off = 1; off < 256; off <<= 1) {
    int t = 0;
    if (tid < 256 && tid >= off) t = sd[tid - off];
    __syncthreads();
    if (tid < 256) sd[tid] += t;
    __syncthreads();
  }
  if (tid < 256) {
    const int ex = sd[tid] - lh[tid];
    cur[tid] = ex;
    rowstart[b * 257 + tid] = (int)rbase + ex;
    if (tid == 0) rowstart[b * 257 + 256] = (int)rbase + cnt;
  }
  __syncthreads();
  for (int i = tid; i < cnt; i += 1024) {
    const ull payv = spc[rbase + i];
    const int dl = (int)((payv >> 48) & 255u);
    const int pos = atomicAdd(&cur[dl], 1);
    pay[pos] = make_int2((int)((payv >> 32) & 0xFFFFu), (int)(unsigned)payv);
  }
  __syncthreads();
  for (int i = tid; i < cnt; i += 1024) spf[rbase + i] = pay[i];
  const int lane = tid & 63, wid = tid >> 6;
  const float a1 = consts[0], c1 = consts[1];
  for (int i = wid; i < 256; i += 16) {
    const int n = (b << 8) + i;
    if (n >= N) break;
    const int rsl = sd[i] - lh[i], ci = lh[i];
    float part = 0.f;
    for (int j = lane; j < ci; j += 64) {
      const int2 pv = pay[rsl + j];
      part += fmaxf(x[pv.x] + fmaf(a1, __int_as_float(pv.y), c1), 0.f);
    }
#pragma unroll
    for (int o = 32; o >= 1; o >>= 1) part += __shfl_xor(part, o, 64);
    if (lane == 0) s1[n] = x[n] + part;
  }
}

// ------------------------- layer 2 (bf16 t2 out) -------------------------
__global__ __launch_bounds__(256) void edge2_csr(
    const int* __restrict__ rowstart, const int2* __restrict__ sp,
    const float* __restrict__ s1, const float* __restrict__ n1w,
    const float* __restrict__ n1b, const float* __restrict__ consts,
    unsigned short* __restrict__ t2b, int N) {
  const int n = (blockIdx.x * blockDim.x + threadIdx.x) >> 6;
  const int lane = threadIdx.x & 63;
  if (n >= N) return;
  const int rbase = (n >> 8) * 257 + (n & 255);
  const int rs = rowstart[rbase], re = rowstart[rbase + 1];
  const float w0 = n1w[lane],            w1 = n1w[lane + 64];
  const float u0 = consts[2 + lane],     u1 = consts[2 + lane + 64];
  const float c0 = consts[2 + H + lane], c1 = consts[2 + H + lane + 64];
  float acc0 = 0.f, acc1 = 0.f;
  for (int base = rs; base < re; base += 64) {
    const int i = base + lane;
    float s1v = 0.f, eav = 0.f;
    if (i < re) {
      const int2 sv = sp[i];
      s1v = s1[sv.x];
      eav = __int_as_float(sv.y);
    }
    const int cnt = min(64, re - base);
    for (int j = 0; j < cnt; ++j) {
      const float s = __shfl(s1v, j, 64);
      const float a = __shfl(eav, j, 64);
      acc0 += fmaxf(fmaf(s, w0, fmaf(a, u0, c0)), 0.f);
      acc1 += fmaxf(fmaf(s, w1, fmaf(a, u1, c1)), 0.f);
    }
  }
  const float sn = s1[n];
  t2b[(size_t)n * H + lane]      = bf16r(fmaf(sn, w0, n1b[lane])      + acc0);
  t2b[(size_t)n * H + lane + 64] = bf16r(fmaf(sn, w1, n1b[lane + 64]) + acc1);
}

// ------------------------- layer 3 (bf16 in/out) -------------------------
__global__ __launch_bounds__(256) void edge3_csr(
    const int* __restrict__ rowstart, const int2* __restrict__ sp,
    const unsigned short* __restrict__ h2b, const float* __restrict__ consts,
    unsigned short* __restrict__ t3b, int N) {
  const int n = (blockIdx.x * blockDim.x + threadIdx.x) >> 6;
  const int lane = threadIdx.x & 63;
  if (n >= N) return;
  const int rbase = (n >> 8) * 257 + (n & 255);
  const int rs = rowstart[rbase], re = rowstart[rbase + 1];
  const int k0 = 2 * lane;
  const float u0 = consts[2 + 2 * H + k0], u1 = consts[2 + 2 * H + k0 + 1];
  const float c0 = consts[2 + 3 * H + k0], c1 = consts[2 + 3 * H + k0 + 1];
  float acc0 = 0.f, acc1 = 0.f;
  int i = rs;
  for (; i + 4 <= re; i += 4) {
    const int2 e0 = sp[i], e1 = sp[i + 1], e2 = sp[i + 2], e3 = sp[i + 3];
    const ushort2 h0 = *(const ushort2*)&h2b[(size_t)e0.x * H + k0];
    const ushort2 h1 = *(const ushort2*)&h2b[(size_t)e1.x * H + k0];
    const ushort2 h2v = *(const ushort2*)&h2b[(size_t)e2.x * H + k0];
    const ushort2 h3 = *(const ushort2*)&h2b[(size_t)e3.x * H + k0];
    const float a0 = __int_as_float(e0.y), a1 = __int_as_float(e1.y);
    const float a2 = __int_as_float(e2.y), a3 = __int_as_float(e3.y);
    acc0 += fmaxf(bf2f(h0.x) + fmaf(a0, u0, c0), 0.f);
    acc1 += fmaxf(bf2f(h0.y) + fmaf(a0, u1, c1), 0.f);
    acc0 += fmaxf(bf2f(h1.x) + fmaf(a1, u0, c0), 0.f);
    acc1 += fmaxf(bf2f(h1.y) + fmaf(a1, u1, c1), 0.f);
    acc0 += fmaxf(bf2f(h2v.x) + fmaf(a2, u0, c0), 0.f);
    acc1 += fmaxf(bf2f(h2v.y) + fmaf(a2, u1, c1), 0.f);
    acc0 += fmaxf(bf2f(h3.x) + fmaf(a3, u0, c0), 0.f);
    acc1 += fmaxf(bf2f(h3.y) + fmaf(a3, u1, c1), 0.f);
  }
  for (; i < re; ++i) {
    const int2 ev = sp[i];
    const ushort2 hv = *(const ushort2*)&h2b[(size_t)ev.x * H + k0];
    const float a = __int_as_float(ev.y);
    acc0 += fmaxf(bf2f(hv.x) + fmaf(a, u0, c0), 0.f);
    acc1 += fmaxf(bf2f(hv.y) + fmaf(a, u1, c1), 0.f);
  }
  const ushort2 hn = *(const ushort2*)&h2b[(size_t)n * H + k0];
  ((unsigned*)t3b)[(size_t)n * 64 + lane] =
      bf16pair(bf2f(hn.x) + acc0, bf2f(hn.y) + acc1);
}

// ------------------------- MFMA node MLPs -------------------------
// h2b[n,:] = bf16(t2b[n,:] @ W2 + b2); wave = 16 nodes x 128 outs
__global__ __launch_bounds__(256) void mlp2_mfma(
    const unsigned short* __restrict__ t2b, unsigned short* __restrict__ h2b,
    const unsigned short* __restrict__ w2t, const float* __restrict__ n2b,
    int N) {
  __shared__ unsigned short dt[4][16 * H];  // 16 KB, per-wave tiles
  const int tid = threadIdx.x, w = tid >> 6, lane = tid & 63;
  const int col = lane & 15, quad = lane >> 4;
  const int tile = blockIdx.x * 4 + w;
  const int node0 = tile * 16;
  const bf16x8* arow =
      (const bf16x8*)(t2b + (size_t)(node0 + col) * H + quad * 8);
  const bf16x8 a0 = arow[0], a1 = arow[4], a2 = arow[8], a3 = arow[12];
#pragma unroll
  for (int t = 0; t < 8; ++t) {
    const bf16x8* bcol =
        (const bf16x8*)(w2t + (size_t)(t * 16 + col) * H + quad * 8);
    f32x4 acc = {0.f, 0.f, 0.f, 0.f};
    acc = __builtin_amdgcn_mfma_f32_16x16x32_bf16(a0, bcol[0], acc, 0, 0, 0);
    acc = __builtin_amdgcn_mfma_f32_16x16x32_bf16(a1, bcol[4], acc, 0, 0, 0);
    acc = __builtin_amdgcn_mfma_f32_16x16x32_bf16(a2, bcol[8], acc, 0, 0, 0);
    acc = __builtin_amdgcn_mfma_f32_16x16x32_bf16(a3, bcol[12], acc, 0, 0, 0);
    const float bias = n2b[t * 16 + col];
#pragma unroll
    for (int r = 0; r < 4; ++r)
      dt[w][(quad * 4 + r) * H + t * 16 + col] = bf16r(acc[r] + bias);
  }
  __syncthreads();
  const unsigned* du = (const unsigned*)dt;    // [64 local nodes][64 words]
  unsigned* gu = (unsigned*)h2b;
  const int nb = blockIdx.x * 64;
  for (int i = tid; i < 64 * 64; i += 256) {
    const int r = i >> 6;
    if (nb + r < N) gu[(size_t)(nb + r) * 64 + (i & 63)] = du[i];
  }
}

// h3 = t3b @ W3 + b3 (f32 in LDS); p=h3.dec_w[:128], q=h3.dec_w[128:]
__global__ __launch_bounds__(256) void mlp3_mfma(
    const unsigned short* __restrict__ t3b, const unsigned short* __restrict__ w3t,
    const float* __restrict__ n3b, const float* __restrict__ dec_w,
    float* __restrict__ p, float* __restrict__ q, int N) {
  __shared__ float dt3[4][16 * H];  // 32 KB, per-wave tiles
  const int tid = threadIdx.x, w = tid >> 6, lane = tid & 63;
  const int col = lane & 15, quad = lane >> 4;
  const int tile = blockIdx.x * 4 + w;
  const int node0 = tile * 16;
  const bf16x8* arow =
      (const bf16x8*)(t3b + (size_t)(node0 + col) * H + quad * 8);
  const bf16x8 a0 = arow[0], a1 = arow[4], a2 = arow[8], a3 = arow[12];
#pragma unroll
  for (int t = 0; t < 8; ++t) {
    const bf16x8* bcol =
        (const bf16x8*)(w3t + (size_t)(t * 16 + col) * H + quad * 8);
    f32x4 acc = {0.f, 0.f, 0.f, 0.f};
    acc = __builtin_amdgcn_mfma_f32_16x16x32_bf16(a0, bcol[0], acc, 0, 0, 0);
    acc = __builtin_amdgcn_mfma_f32_16x16x32_bf16(a1, bcol[4], acc, 0, 0, 0);
    acc = __builtin_amdgcn_mfma_f32_16x16x32_bf16(a2, bcol[8], acc, 0, 0, 0);
    acc = __builtin_amdgcn_mfma_f32_16x16x32_bf16(a3, bcol[12], acc, 0, 0, 0);
    const float bias = n3b[t * 16 + col];
#pragma unroll
    for (int r = 0; r < 4; ++r)
      dt3[w][(quad * 4 + r) * H + t * 16 + col] = acc[r] + bias;
  }
  __syncthreads();
  const float dwA0 = dec_w[lane], dwA1 = dec_w[64 + lane];
  const float dwB0 = dec_w[128 + lane], dwB1 = dec_w[192 + lane];
#pragma unroll 4
  for (int r = 0; r < 16; ++r) {
    const float h0 = dt3[w][r * H + lane];
    const float h1 = dt3[w][r * H + 64 + lane];
    float pd = h0 * dwA0 + h1 * dwA1;
    float qd = h0 * dwB0 + h1 * dwB1;
#pragma unroll
    for (int o = 32; o >= 1; o >>= 1) {
      pd += __shfl_xor(pd, o, 64);
      qd += __shfl_xor(qd, o, 64);
    }
    const int n = node0 + r;
    if (lane == 0 && n < N) { p[n] = pd; q[n] = qd; }
  }
}

__global__ void final_kernel(const int* __restrict__ src,
                             const int* __restrict__ dst,
                             const float* __restrict__ p,
                             const float* __restrict__ q,
                             const float* __restrict__ dec_b,
                             float* __restrict__ out, int E) {
  const int e = blockIdx.x * blockDim.x + threadIdx.x;
  if (e < E) out[e] = p[src[e]] + q[dst[e]] + dec_b[0];
}

extern "C" void kernel_launch(void* const* d_in, const int* in_sizes, int n_in,
                              void* d_out, int out_size, void* d_ws, size_t ws_size,
                              hipStream_t stream) {
  const float* x     = (const float*)d_in[0];
  const int*   ei    = (const int*)d_in[1];
  const float* ea    = (const float*)d_in[2];
  const float* em_w  = (const float*)d_in[3];
  const float* em_b  = (const float*)d_in[4];
  const float* l1_w  = (const float*)d_in[5];
  const float* l1_b  = (const float*)d_in[6];
  const float* n1_w  = (const float*)d_in[7];
  const float* n1_b  = (const float*)d_in[8];
  const float* l2_w  = (const float*)d_in[9];
  const float* l2_b  = (const float*)d_in[10];
  const float* n2_w  = (const float*)d_in[11];
  const float* n2_b  = (const float*)d_in[12];
  const float* l3_w  = (const float*)d_in[13];
  const float* l3_b  = (const float*)d_in[14];
  const float* n3_w  = (const float*)d_in[15];
  const float* n3_b  = (const float*)d_in[16];
  const float* dec_w = (const float*)d_in[17];
  const float* dec_b = (const float*)d_in[18];
  float* out = (float*)d_out;

  const int N = in_sizes[0];
  const int E = in_sizes[2];
  const int* src = ei;
  const int* dst = ei + E;

  const int NBUCK  = (N + 255) >> 8;     // 196
  const int NBATCH = (E + 2047) >> 11;   // 391
  const int NPAD   = ((N + 63) / 64) * 64;  // 50048
  const int NBLK64 = NPAD / 64;          // 782 blocks for MFMA MLPs

  float* ws       = (float*)d_ws;
  float* consts   = ws;                              // 1024 f
  ull*   spc      = (ull*)(ws + 1024);               // NBUCK*CAP u64
  int2*  spf      = (int2*)(spc + (size_t)NBUCK * CAPC);
  unsigned short* t2b = (unsigned short*)(spf + (size_t)NBUCK * CAPC); // NPAD*H
  unsigned short* t3b = t2b + (size_t)NPAD * H;      // NPAD*H bf16
  unsigned short* h2b = t3b + (size_t)NPAD * H;      // NPAD*H bf16
  unsigned short* w2t = h2b + (size_t)NPAD * H;      // H*H bf16
  unsigned short* w3t = w2t + H * H;                 // H*H bf16
  float* s1       = (float*)(w3t + H * H);
  float* p        = s1 + N;
  float* q        = p + N;
  int*   cursor   = (int*)(q + N);                   // 256
  int*   rowstart = cursor + 256;                    // NBUCK*257

  init_consts<<<129, 256, 0, stream>>>(em_w, em_b, l1_w, l1_b, l2_w, l2_b,
                                       n1_b, l3_w, l3_b, n2_w, n3_w,
                                       consts, cursor, w2t, w3t, NBUCK);
  bin_scatter<<<NBATCH, 1024, 0, stream>>>(src, dst, ea, cursor, spc, E, NBUCK);
  fine_scatter<<<NBUCK, 1024, 0, stream>>>(cursor, spc, x, consts, spf,
                                           rowstart, s1, N);

  const int nwblocks = (N + 3) / 4;  // 4 waves (nodes) per 256-thread block
  edge2_csr<<<nwblocks, 256, 0, stream>>>(rowstart, spf, s1, n1_w, n1_b,
                                          consts, t2b, N);
  mlp2_mfma<<<NBLK64, 256, 0, stream>>>(t2b, h2b, w2t, n2_b, N);
  edge3_csr<<<nwblocks, 256, 0, stream>>>(rowstart, spf, h2b, consts, t3b, N);
  mlp3_mfma<<<NBLK64, 256, 0, stream>>>(t3b, w3t, n3_b, dec_w, p, q, N);
  final_kernel<<<(E + 255) / 256, 256, 0, stream>>>(src, dst, p, q, dec_b, out, E);
}